// Round 6
// baseline (123.977 us; speedup 1.0000x reference)
//
#include <hip/hip_runtime.h>
#include <hip/hip_bf16.h>
#include <math.h>

#define INPUT_DIM 256
#define OUT_DIM   256
#define NDEG      8                    // degree+1
#define KTOT      (INPUT_DIM * NDEG)   // 2048
#define NROWS     (16 * 2048)          // 32768

#define BM  64
#define BN  256                        // whole output dim: featurize once per x elem
#define BK  64                         // 8 inputs * 8 degrees per K-chunk
#define NK  (KTOT / BK)                // 32
#define ACH 4096                       // A chunk elems: 64 m * 64 k  (8 KB)
#define BCH 16384                      // B chunk elems: 256 o * 64 k (32 KB)

typedef __bf16 bf16x8 __attribute__((ext_vector_type(8)));
typedef float  f32x4  __attribute__((ext_vector_type(4)));

// ---------------------------------------------------------------------------
// Kernel 1: reorder + swizzle coeffs C[i][o][d] (fp32) -> Bt_sw (bf16).
// Panel layout, the exact linear LDS image for global_load_lds:
//   chunk(kc) base = kc*16384; elem offset = p*2048 + o*8 + r
//   (p = i&7 input-in-chunk, r = d).
// ---------------------------------------------------------------------------
__global__ __launch_bounds__(256) void reorder_coeffs(const float* __restrict__ C,
                                                      __bf16* __restrict__ Bt) {
    int g = blockIdx.x * 256 + threadIdx.x;   // 65536 = 256 i * 256 o
    int i = g >> 8;
    int o = g & 255;
    const float4* src = (const float4*)(C + (size_t)i * (OUT_DIM * NDEG) + o * NDEG);
    float4 a = src[0];
    float4 b = src[1];
    bf16x8 v;
    v[0] = (__bf16)a.x; v[1] = (__bf16)a.y; v[2] = (__bf16)a.z; v[3] = (__bf16)a.w;
    v[4] = (__bf16)b.x; v[5] = (__bf16)b.y; v[6] = (__bf16)b.z; v[7] = (__bf16)b.w;
    int kc = i >> 3;          // K-chunk
    int p  = i & 7;           // input-in-chunk (panel)
    size_t dst = (size_t)kc * BCH + p * 2048 + o * 8;
    *(bf16x8*)(Bt + dst) = v;   // 16B-aligned
}

// ---------------------------------------------------------------------------
// Kernel 2: fused tanh + Hermite featurize + bf16 MFMA GEMM.
// Round 6: single-barrier double-buffered pipeline. Per iteration kc:
//   glds B(kc+1)->Bbuf^1 (in flight across the whole compute phase),
//   featurize chunk kc+1 (xs prefetched last iter, 1 VGPR) -> Abuf^1
//   in the MFMA shadow of chunk kc, then ONE __syncthreads.
// A uses the same panel layout as B ([p][m][r], unpadded): featurize writes
// are wave-contiguous (conflict-free), frag reads are 256B-contiguous
// 16-lane segments (same clean pattern as B).
// LDS 2x32K + 2x8K = 81920 B exactly -> 2 blocks/CU, 16 waves/CU.
// Tile 64x256, 8 waves of 32x64, grid 512.
// ---------------------------------------------------------------------------
__global__ __launch_bounds__(512, 4) void hermite_mfma(const float* __restrict__ x,
                                                       const __bf16* __restrict__ Bt,
                                                       float* __restrict__ out) {
    __shared__ __align__(16) __bf16 Alds[2][ACH];   // 2 x  8 KB
    __shared__ __align__(16) __bf16 Blds[2][BCH];   // 2 x 32 KB   (80 KiB total)

    const int tid  = threadIdx.x;
    const int bm   = blockIdx.x;         // 0..511
    const int wave = tid >> 6;           // 0..7
    const int lane = tid & 63;
    const int wr   = (wave >> 2) * 32;   // wave row origin (0,32)
    const int wc   = (wave & 3) * 64;    // wave col origin (0,64,128,192)
    const int lrow = lane & 15;
    const int quad = lane >> 4;

    // Featurize mapping: wave handles panel p=wave, lane handles row m=lane.
    // LDS write addr = tid*16 B -> block-contiguous, conflict-free.
    const float* xp = x + (size_t)(bm * BM + lane) * INPUT_DIM + wave;

    // B staging: wave w DMAs bytes [w*4K, w*4K+4K) of the 32 KB chunk
    const int wbase = wave * 2048 + lane * 8;   // elems (per-lane 16 B)

    f32x4 acc[2][4] = {};

#define FEATURIZE(XS, DST)                                                  \
    {                                                                       \
        float e = __expf(2.0f * (XS));          /* tanh robust for all x */ \
        float t = 1.0f - 2.0f / (e + 1.0f);                                 \
        bf16x8 v;                                                           \
        float hm2 = 1.0f;                       /* H_0 */                   \
        float hm1 = 2.0f * t;                   /* H_1 */                   \
        v[0] = (__bf16)hm2;                                                 \
        v[1] = (__bf16)hm1;                                                 \
        _Pragma("unroll")                                                   \
        for (int d = 2; d < 8; ++d) {                                       \
            float h = 2.0f * t * hm1 - 2.0f * (float)(d - 1) * hm2;         \
            v[d] = (__bf16)h;                                               \
            hm2 = hm1; hm1 = h;                                             \
        }                                                                   \
        *(bf16x8*)(DST) = v;                                                \
    }

    // ---- prologue: stage chunk 0, prefetch xs for chunk 1 ----
    float xs = xp[0];
    {
        const __bf16* g = Bt + wbase;
        #pragma unroll
        for (int i = 0; i < 4; ++i)
            __builtin_amdgcn_global_load_lds(
                (const __attribute__((address_space(1))) void*)(g + i * 512),
                (__attribute__((address_space(3))) void*)(&Blds[0][wbase + i * 512]),
                16, 0, 0);
    }
    FEATURIZE(xs, &Alds[0][tid * 8]);
    xs = xp[8];   // chunk 1
    __syncthreads();

    for (int kc = 0; kc < NK; ++kc) {
        const int buf  = kc & 1;
        const int nbuf = buf ^ 1;

        if (kc + 1 < NK) {
            // ---- prefetch B(kc+1): in flight across the whole compute phase ----
            const __bf16* g = Bt + (size_t)(kc + 1) * BCH + wbase;
            #pragma unroll
            for (int i = 0; i < 4; ++i)
                __builtin_amdgcn_global_load_lds(
                    (const __attribute__((address_space(1))) void*)(g + i * 512),
                    (__attribute__((address_space(3))) void*)(&Blds[nbuf][wbase + i * 512]),
                    16, 0, 0);

            // ---- featurize chunk kc+1 in the MFMA shadow ----
            FEATURIZE(xs, &Alds[nbuf][tid * 8]);
            int kn = (kc + 2 < NK) ? kc + 2 : NK - 1;
            xs = xp[kn * 8];
        }

        // ---- MFMA on chunk kc: 2 k-steps of 32, 2x4 frags per wave ----
        #pragma unroll
        for (int ki = 0; ki < 2; ++ki) {
            bf16x8 af[2], bfr[4];
            #pragma unroll
            for (int mi = 0; mi < 2; ++mi)
                af[mi] = *(const bf16x8*)(&Alds[buf][((ki * 4 + quad) * 64 + wr + mi * 16 + lrow) * 8]);
            #pragma unroll
            for (int ni = 0; ni < 4; ++ni)
                bfr[ni] = *(const bf16x8*)(&Blds[buf][((ki * 4 + quad) * 256 + wc + ni * 16 + lrow) * 8]);
            #pragma unroll
            for (int mi = 0; mi < 2; ++mi)
                #pragma unroll
                for (int ni = 0; ni < 4; ++ni)
                    acc[mi][ni] = __builtin_amdgcn_mfma_f32_16x16x32_bf16(
                        af[mi], bfr[ni], acc[mi][ni], 0, 0, 0);
        }

        __syncthreads();   // ONE barrier/iter: drains glds+feat writes (nbuf) and frag reads (buf)
    }

    // ---- epilogue: C/D layout col=lane&15, row=quad*4+reg (m89-verified) ----
    #pragma unroll
    for (int mi = 0; mi < 2; ++mi) {
        #pragma unroll
        for (int r = 0; r < 4; ++r) {
            int row = bm * BM + wr + mi * 16 + quad * 4 + r;
            float* orow = out + (size_t)row * OUT_DIM + wc + lrow;
            #pragma unroll
            for (int ni = 0; ni < 4; ++ni)
                orow[ni * 16] = acc[mi][ni][r];
        }
    }
#undef FEATURIZE
}

// ---------------------------------------------------------------------------
extern "C" void kernel_launch(void* const* d_in, const int* in_sizes, int n_in,
                              void* d_out, int out_size, void* d_ws, size_t ws_size,
                              hipStream_t stream) {
    const float* x = (const float*)d_in[0];          // [16,2048,256] fp32
    const float* C = (const float*)d_in[1];          // [256,256,8]  fp32
    float* out = (float*)d_out;                      // [16,2048,256] fp32
    __bf16* Bt = (__bf16*)d_ws;                      // swizzled [32][16384] bf16, 1 MB scratch

    reorder_coeffs<<<dim3((INPUT_DIM * OUT_DIM) / 256), dim3(256), 0, stream>>>(C, Bt);
    hermite_mfma<<<dim3(NROWS / BM), dim3(512), 0, stream>>>(x, Bt, out);
}